// Round 10
// baseline (1407.039 us; speedup 1.0000x reference)
//
#include <hip/hip_runtime.h>
#include <hip/hip_bf16.h>
#include <math.h>

// MDN-RNN: B=128, T=512, Z=32, A=3, H=256, K=5, IN=35, 4H=1024, MDN=325
#define T_LEN 512
#define B_SZ  128
#define H_DIM 256
#define G_DIM 1024
#define IN_D  35
#define MDN_D 325
#define K_MIX 5

#define NSLICE 4     // gate-dim slices per group (each owns 64 h-cols x 4 gates)
#define BG     2     // batches per group
#define NGRP   64    // 128 / BG   -> 256 blocks total = 1/CU

// d_out layout: log_pi[B,T,5] | mu[B,T,5,32] | sigma[B,T,5,32] | c[B,256] | h[B,256]
static constexpr long OFF_MU    = 327680L;
static constexpr long OFF_SIGMA = 10813440L;
static constexpr long OFF_C     = 21299200L;
static constexpr long OFF_H     = 21331968L;

// ws layout (~34 MB; ws >= 64 MiB proven in round 1)
static constexpr size_t WS_OUT = 0;          // bf16 outs: B*T*H*2 = 33,554,432 B
static constexpr size_t WS_HG  = 33554432;   // 64 grp * 2 par * 2 b * 256 f32 = 512 KB

typedef unsigned uint2v  __attribute__((ext_vector_type(2)));
typedef float    float2v __attribute__((ext_vector_type(2)));

__device__ __forceinline__ float fast_sigmoid(float x) { return 1.0f / (1.0f + __expf(-x)); }
__device__ __forceinline__ float fast_tanh(float x) {
    return 1.0f - 2.0f / (__expf(2.0f * x) + 1.0f);
}

// acc.lo += w.lo*h.lo ; acc.hi += w.hi*h.lo   (broadcast LOW half of h-pair)
__device__ __forceinline__ void pk_fma_lo(float2v& acc, float2v w, float2v h) {
    asm("v_pk_fma_f32 %0, %1, %2, %0 op_sel:[0,0,0] op_sel_hi:[1,0,1]"
        : "+v"(acc) : "v"(w), "v"(h));
}
// acc.lo += w.lo*h.hi ; acc.hi += w.hi*h.hi   (broadcast HIGH half of h-pair)
__device__ __forceinline__ void pk_fma_hi(float2v& acc, float2v w, float2v h) {
    asm("v_pk_fma_f32 %0, %1, %2, %0 op_sel:[0,1,0] op_sel_hi:[1,1,1]"
        : "+v"(acc) : "v"(w), "v"(h));
}

// f32 bits -> bf16 (round-to-nearest-even); h is finite, no NaN handling needed
__device__ __forceinline__ unsigned f2bf(unsigned u) {
    return (u + 0x7FFFu + ((u >> 16) & 1u)) >> 16;
}
// one dword of 2 packed bf16 -> float2v (lo16 -> .x, hi16 -> .y); 2 VALU ops
__device__ __forceinline__ float2v bf2pair(unsigned d) {
    float2v r;
    r.x = __uint_as_float(d << 16);
    r.y = __uint_as_float(d & 0xFFFF0000u);
    return r;
}

// r9 structure with ONE change: h in LDS is bf16 (halves the dominant LDS-read
// term: 32 -> 16 ds_read_b128/thread/step; unpack moves to the idle VALU pipe).
// 256 blocks (group=bid&63, slice=bid>>6), 512 threads; weights VGPR-resident
// (pinned). Waves 0-1 = writers (publish fp32-tagged h, never poll), waves 2-4 =
// pollers (zero stores; 2-deep pipelined probe), wave 6 = x stagers.
__global__ __launch_bounds__(512, 1) void lstm10_kernel(
    const float* __restrict__ z_t, const float* __restrict__ a_t,
    const float* __restrict__ Wx,  const float* __restrict__ Wh,
    const float* __restrict__ bias,
    float* __restrict__ h_glb,
    __hip_bfloat16* __restrict__ outs,
    float* __restrict__ out_c, float* __restrict__ out_h)
{
    const int bid = blockIdx.x;
    const int gr  = bid & 63;
    const int s   = bid >> 6;
    const int tid = threadIdx.x;
    const int cg  = tid >> 2;              // cols {2cg, 2cg+1} of this 256-col slice
    const int kq  = tid & 3;               // k-range [kq*64, kq*64+64)
    const int lc0 = cg * 2;
    const int gate = lc0 >> 6;
    const int j0   = lc0 & 63;
    const int gcol0 = gate * 256 + s * 64 + j0;

    // h as bf16: [batch][kq section][64 used + 16 pad] -> sections 160B apart,
    // 16B aligned; a wave's b128 read hits 4 distinct banks-sets, conflict-free.
    __shared__ __align__(16) unsigned short h_bf[BG][4][80];
    __shared__ __align__(16) float x_lds[2][BG][44];   // double-buffered x (fp32)
    __shared__ __align__(16) float g_red[BG][256];

    for (int i = tid; i < (BG * 4 * 80) / 2; i += 512) ((unsigned*)h_bf)[i] = 0u;
    if (tid < 2 * BG * 9) {   // zero x pads [35..43] both parities
        int buf = tid / 18, r = tid % 18, b = r / 9, k = 35 + r % 9;
        x_lds[buf][b][k] = 0.0f;
    }

    // ---- persistent weights in VGPRs (loaded once, pinned vs remat) ----
    float2v W2[64];
    #pragma unroll
    for (int i = 0; i < 64; ++i) {
        const size_t r = (size_t)(kq * 64 + i) * G_DIM;
        W2[i].x = Wh[r + gcol0];
        W2[i].y = Wh[r + gcol0 + 1];
    }
    float2v X2[10];
    #pragma unroll
    for (int i = 0; i < 10; ++i) {
        int xk = kq * 10 + i;
        bool ok = (xk < IN_D);
        X2[i].x = ok ? Wx[(size_t)xk * G_DIM + gcol0]     : 0.0f;
        X2[i].y = ok ? Wx[(size_t)xk * G_DIM + gcol0 + 1] : 0.0f;
    }
    #pragma unroll
    for (int i = 0; i < 64; ++i) asm volatile("" : "+v"(W2[i]));
    #pragma unroll
    for (int i = 0; i < 10; ++i) asm volatile("" : "+v"(X2[i]));

    // writer role (tid<128): batch cb, h-col cj of this slice
    const int cb = tid >> 6;
    const int cj = tid & 63;
    const float bc0 = bias[0 * 256 + s * 64 + cj];
    const float bc1 = bias[1 * 256 + s * 64 + cj];
    const float bc2 = bias[2 * 256 + s * 64 + cj];
    const float bc3 = bias[3 * 256 + s * 64 + cj];
    float c_reg = 0.0f;

    // poller role (tid in [128,320)): q -> foreign dword pair (b, kk)
    const int q  = tid - 128;              // 0..191
    const int pb = (q >= 96) ? 1 : 0;
    const int pp = q - 96 * pb;            // 0..95
    const int pk0 = pp * 2;
    const int pkk = pk0 + ((pk0 >= s * 64) ? 64 : 0);   // skip own slice's 64-chunk

    const int batch0 = gr * BG;
    float* hg = h_glb + (size_t)gr * (2 * BG * H_DIM);   // [2][BG][256]

    // ---- pre-loop: stage x(0) ----
    if (tid >= 384 && tid < 448) {
        int qq = tid - 384, b = qq >> 5, k = qq & 31;
        x_lds[0][b][k] = z_t[((size_t)(batch0 + b) * T_LEN + 0) * 32 + k];
    } else if (tid >= 448 && tid < 448 + BG * 3) {
        int qq = tid - 448, b = (qq >= 3), k = qq - 3 * b;
        x_lds[0][b][32 + k] = a_t[((size_t)(batch0 + b) * T_LEN + 0) * 3 + k];
    }
    __syncthreads();

    for (int t = 0; t < T_LEN; ++t) {
        // ---- (A) 2-deep pipelined poll of foreign tagged h(t-1) pairs ----
        if (t > 0 && tid >= 128 && tid < 320) {
            const unsigned want = (unsigned)((t - 1) & 3);
            const float* ap = hg + ((t - 1) & 1) * (BG * H_DIM) + pb * H_DIM + pkk;
            uint2v u0, u1, got;
            asm volatile("global_load_dwordx2 %0, %1, off sc0 sc1"
                         : "=v"(u0) : "v"(ap) : "memory");
            for (;;) {
                asm volatile("global_load_dwordx2 %0, %1, off sc0 sc1"
                             : "=v"(u1) : "v"(ap) : "memory");
                asm volatile("s_waitcnt vmcnt(1)" : "+v"(u0) :: "memory");
                if ((u0.x & 3u) == want && (u0.y & 3u) == want) { got = u0; break; }
                asm volatile("global_load_dwordx2 %0, %1, off sc0 sc1"
                             : "=v"(u0) : "v"(ap) : "memory");
                asm volatile("s_waitcnt vmcnt(1)" : "+v"(u1) :: "memory");
                if ((u1.x & 3u) == want && (u1.y & 3u) == want) { got = u1; break; }
            }
            asm volatile("s_waitcnt vmcnt(0)" ::: "memory");  // drain the extra probe
            // convert pair to packed bf16 (tag bits truncate away) + one b32 write
            unsigned packed = f2bf(got.x) | (f2bf(got.y) << 16);
            *(unsigned*)&h_bf[pb][pkk >> 6][pkk & 63] = packed;
        }
        __syncthreads();   // B1: h_bf + x_lds(t) ready

        // ---- (B) packed FMA: 2 batches x col-pair x 64 k (bf16 h, fp32 W) ----
        float2v acc0 = {0.0f, 0.0f}, acc1 = {0.0f, 0.0f};
        {
            const uint4* hq0 = (const uint4*)&h_bf[0][kq][0];
            const uint4* hq1 = (const uint4*)&h_bf[1][kq][0];
            #pragma unroll
            for (int i8 = 0; i8 < 8; ++i8) {
                uint4 d0 = hq0[i8];
                uint4 d1 = hq1[i8];
                float2v p;
                p = bf2pair(d0.x); pk_fma_lo(acc0, W2[8*i8+0], p); pk_fma_hi(acc0, W2[8*i8+1], p);
                p = bf2pair(d0.y); pk_fma_lo(acc0, W2[8*i8+2], p); pk_fma_hi(acc0, W2[8*i8+3], p);
                p = bf2pair(d0.z); pk_fma_lo(acc0, W2[8*i8+4], p); pk_fma_hi(acc0, W2[8*i8+5], p);
                p = bf2pair(d0.w); pk_fma_lo(acc0, W2[8*i8+6], p); pk_fma_hi(acc0, W2[8*i8+7], p);
                p = bf2pair(d1.x); pk_fma_lo(acc1, W2[8*i8+0], p); pk_fma_hi(acc1, W2[8*i8+1], p);
                p = bf2pair(d1.y); pk_fma_lo(acc1, W2[8*i8+2], p); pk_fma_hi(acc1, W2[8*i8+3], p);
                p = bf2pair(d1.z); pk_fma_lo(acc1, W2[8*i8+4], p); pk_fma_hi(acc1, W2[8*i8+5], p);
                p = bf2pair(d1.w); pk_fma_lo(acc1, W2[8*i8+6], p); pk_fma_hi(acc1, W2[8*i8+7], p);
            }
            #pragma unroll
            for (int i = 0; i < 5; ++i) {
                float2v xv0 = *(const float2v*)&x_lds[t & 1][0][kq * 10 + 2 * i];
                float2v xv1 = *(const float2v*)&x_lds[t & 1][1][kq * 10 + 2 * i];
                pk_fma_lo(acc0, X2[2*i],   xv0); pk_fma_lo(acc1, X2[2*i],   xv1);
                pk_fma_hi(acc0, X2[2*i+1], xv0); pk_fma_hi(acc1, X2[2*i+1], xv1);
            }
        }
        float a00 = acc0.x, a01 = acc0.y, a10 = acc1.x, a11 = acc1.y;
        // k-reduce across the 4 kq lanes of each quad
        a00 += __shfl_xor(a00, 1, 64); a00 += __shfl_xor(a00, 2, 64);
        a01 += __shfl_xor(a01, 1, 64); a01 += __shfl_xor(a01, 2, 64);
        a10 += __shfl_xor(a10, 1, 64); a10 += __shfl_xor(a10, 2, 64);
        a11 += __shfl_xor(a11, 1, 64); a11 += __shfl_xor(a11, 2, 64);
        if (kq == 0) {
            g_red[0][lc0] = a00; g_red[0][lc0 + 1] = a01;
            g_red[1][lc0] = a10; g_red[1][lc0 + 1] = a11;
        }
        __syncthreads();   // B2: g_red ready; FMA reads of h_bf/x_lds done

        // ---- (C) writers: nonlin + c/h update + tagged publish + local h_bf ----
        if (tid < 128) {
            float gi = g_red[cb][      cj] + bc0;
            float gf = g_red[cb][ 64 + cj] + bc1;
            float gg = g_red[cb][128 + cj] + bc2;
            float go = g_red[cb][192 + cj] + bc3;
            float iv = fast_sigmoid(gi), fv = fast_sigmoid(gf), ov = fast_sigmoid(go);
            float gv = fast_tanh(gg);
            c_reg = fmaf(fv, c_reg, iv * gv);
            float hv = ov * fast_tanh(c_reg);
            unsigned u = (__float_as_uint(hv) & ~3u) | (unsigned)(t & 3);
            float* dst = hg + (t & 1) * (BG * H_DIM) + cb * H_DIM + s * 64 + cj;
            asm volatile("global_store_dword %0, %1, off sc0 sc1"
                         :: "v"(dst), "v"(u) : "memory");
            h_bf[cb][s][cj] = (unsigned short)f2bf(u);   // own slice, no IC trip
            outs[((size_t)(batch0 + cb) * T_LEN + t) * H_DIM + s * 64 + cj] =
                __float2bfloat16(hv);
            if (t == T_LEN - 1) {
                out_c[(batch0 + cb) * H_DIM + s * 64 + cj] = c_reg;
                out_h[(batch0 + cb) * H_DIM + s * 64 + cj] = hv;
            }
        }
        // ---- (C) stagers: x(t+1) -> other parity (FMA readers are past B2) ----
        if (t + 1 < T_LEN) {
            if (tid >= 384 && tid < 448) {
                int qq = tid - 384, b = qq >> 5, k = qq & 31;
                x_lds[(t + 1) & 1][b][k] =
                    z_t[((size_t)(batch0 + b) * T_LEN + (t + 1)) * 32 + k];
            } else if (tid >= 448 && tid < 448 + BG * 3) {
                int qq = tid - 448, b = (qq >= 3), k = qq - 3 * b;
                x_lds[(t + 1) & 1][b][32 + k] =
                    a_t[((size_t)(batch0 + b) * T_LEN + (t + 1)) * 3 + k];
            }
        }
        // next iteration's B1 orders all LDS writes; pollers gate on foreign stores
    }
}

// mdn = outputs(bf16) @ Wd + bd, fused log_softmax(log_pi) and exp(log_sigma)+1e-6.
// (reverted to the proven 16-row version from round 6: ~107 us)
__global__ __launch_bounds__(256, 1) void mdn_kernel(
    const unsigned short* __restrict__ outputs, const float* __restrict__ Wd,
    const float* __restrict__ bd, float* __restrict__ out)
{
    __shared__ __align__(16) float hT[H_DIM * 16];   // hT[k*16 + r]
    __shared__ float lp[16][K_MIX];

    const int tid = threadIdx.x;
    const long row0 = (long)blockIdx.x * 16;

    for (int idx = tid; idx < H_DIM * 16; idx += 256) {
        int r = idx >> 8;
        int k = idx & (H_DIM - 1);
        unsigned int u = outputs[(row0 + r) * H_DIM + k];
        hT[k * 16 + r] = __uint_as_float(u << 16);
    }
    __syncthreads();

    const int  cA = tid;
    const int  cB = tid + 256;
    const bool vB = (cB < MDN_D);
    const float bA = bd[cA];
    const float bB = vB ? bd[cB] : 0.0f;
    float accA[16], accB[16];
    #pragma unroll
    for (int r = 0; r < 16; ++r) { accA[r] = bA; accB[r] = bB; }

    for (int k = 0; k < H_DIM; ++k) {
        float wA = Wd[(size_t)k * MDN_D + cA];
        float wB = vB ? Wd[(size_t)k * MDN_D + cB] : 0.0f;
        const float4* hp = (const float4*)(hT + k * 16);
        float4 h0 = hp[0], h1 = hp[1], h2 = hp[2], h3 = hp[3];
        float hr[16] = { h0.x,h0.y,h0.z,h0.w, h1.x,h1.y,h1.z,h1.w,
                         h2.x,h2.y,h2.z,h2.w, h3.x,h3.y,h3.z,h3.w };
        #pragma unroll
        for (int r = 0; r < 16; ++r) {
            accA[r] = fmaf(hr[r], wA, accA[r]);
            accB[r] = fmaf(hr[r], wB, accB[r]);
        }
    }

    float* out_mu = out + OFF_MU;
    float* out_sg = out + OFF_SIGMA;
    #pragma unroll
    for (int r = 0; r < 16; ++r) {
        long row = row0 + r;
        float v = accA[r];
        if (cA < K_MIX)            lp[r][cA] = v;
        else if (cA < K_MIX + 160) out_mu[row * 160 + (cA - K_MIX)] = v;
        else                       out_sg[row * 160 + (cA - 165)]   = __expf(v) + 1e-6f;
        if (vB)                    out_sg[row * 160 + (cB - 165)]   = __expf(accB[r]) + 1e-6f;
    }
    __syncthreads();

    if (tid < 16) {
        int r = tid;
        long row = row0 + r;
        float v0 = lp[r][0], v1 = lp[r][1], v2 = lp[r][2], v3 = lp[r][3], v4 = lp[r][4];
        float m = fmaxf(fmaxf(fmaxf(v0, v1), fmaxf(v2, v3)), v4);
        float sum = __expf(v0-m) + __expf(v1-m) + __expf(v2-m) + __expf(v3-m) + __expf(v4-m);
        float ls = m + __logf(sum);
        out[row*5 + 0] = v0 - ls;
        out[row*5 + 1] = v1 - ls;
        out[row*5 + 2] = v2 - ls;
        out[row*5 + 3] = v3 - ls;
        out[row*5 + 4] = v4 - ls;
    }
}

extern "C" void kernel_launch(void* const* d_in, const int* in_sizes, int n_in,
                              void* d_out, int out_size, void* d_ws, size_t ws_size,
                              hipStream_t stream)
{
    const float* z_t = (const float*)d_in[0];
    const float* a_t = (const float*)d_in[1];
    const float* Wx  = (const float*)d_in[2];
    const float* Wh  = (const float*)d_in[3];
    const float* b   = (const float*)d_in[4];
    const float* Wd  = (const float*)d_in[5];
    const float* bd  = (const float*)d_in[6];
    float* out = (float*)d_out;

    char* ws = (char*)d_ws;
    __hip_bfloat16* outs = (__hip_bfloat16*)(ws + WS_OUT);
    float* h_glb         = (float*)(ws + WS_HG);

    lstm10_kernel<<<NGRP * NSLICE, 512, 0, stream>>>(z_t, a_t, Wx, Wh, b,
                                                     h_glb, outs,
                                                     out + OFF_C, out + OFF_H);
    mdn_kernel<<<(B_SZ * T_LEN) / 16, 256, 0, stream>>>((const unsigned short*)outs,
                                                        Wd, bd, out);
}

// Round 11
// 1254.849 us; speedup vs baseline: 1.1213x; 1.1213x over previous
//
#include <hip/hip_runtime.h>
#include <hip/hip_bf16.h>
#include <math.h>

// MDN-RNN: B=128, T=512, Z=32, A=3, H=256, K=5, IN=35, 4H=1024, MDN=325
#define T_LEN 512
#define B_SZ  128
#define H_DIM 256
#define G_DIM 1024
#define IN_D  35
#define MDN_D 325
#define K_MIX 5

#define NSLICE 4     // gate-dim slices per group
#define NGRP   64    // groups of 2 batches -> 256 blocks = 1/CU

// d_out layout: log_pi[B,T,5] | mu[B,T,5,32] | sigma[B,T,5,32] | c[B,256] | h[B,256]
static constexpr long OFF_MU    = 327680L;
static constexpr long OFF_SIGMA = 10813440L;
static constexpr long OFF_C     = 21299200L;
static constexpr long OFF_H     = 21331968L;

// ws layout (~34 MB; ws >= 64 MiB proven in round 1)
static constexpr size_t WS_OUT = 0;          // bf16 outs: B*T*H*2 = 33,554,432 B
static constexpr size_t WS_HG  = 33554432;   // 64 grp * 2 chains * 2 par * 256 f32 = 512 KB

typedef float float2v __attribute__((ext_vector_type(2)));
typedef float float4v __attribute__((ext_vector_type(4)));

__device__ __forceinline__ float fast_sigmoid(float x) { return 1.0f / (1.0f + __expf(-x)); }
__device__ __forceinline__ float fast_tanh(float x) {
    return 1.0f - 2.0f / (__expf(2.0f * x) + 1.0f);
}

// acc.lo += w.lo*h.lo ; acc.hi += w.hi*h.lo   (broadcast LOW half of h-pair)
__device__ __forceinline__ void pk_fma_lo(float2v& acc, float2v w, float2v h) {
    asm("v_pk_fma_f32 %0, %1, %2, %0 op_sel:[0,0,0] op_sel_hi:[1,0,1]"
        : "+v"(acc) : "v"(w), "v"(h));
}
// acc.lo += w.lo*h.hi ; acc.hi += w.hi*h.hi   (broadcast HIGH half of h-pair)
__device__ __forceinline__ void pk_fma_hi(float2v& acc, float2v w, float2v h) {
    asm("v_pk_fma_f32 %0, %1, %2, %0 op_sel:[0,1,0] op_sel_hi:[1,1,1]"
        : "+v"(acc) : "v"(w), "v"(h));
}

// TWO-CHAIN pipelined LSTM. Block (gr,s): slice s of batches {2gr, 2gr+1} = chains
// A,B — independent recurrences sharing the VGPR-resident weights. Per iteration:
//   check P_A -> B1a -> FMA_A (issue P_B probes mid-FMA; stagers issue x(t+2))
//   -> B2a -> {wave0: nonlin+publish A(t)} {pollers: check P_B} {stagers: x->LDS}
//   -> B1b -> FMA_B (issue P_A probes for h_A(t) mid-FMA)
//   -> B2b -> {wave1: nonlin+publish B(t)}
// Probes complete at the compiler's pre-barrier vmcnt(0) drain -> checks are free
// register compares; serial spin only on (rare) miss. Exchange latency is hidden
// under the other chain's compute instead of serializing the whole block.
__global__ __launch_bounds__(512, 1) void lstm11_kernel(
    const float* __restrict__ z_t, const float* __restrict__ a_t,
    const float* __restrict__ Wx,  const float* __restrict__ Wh,
    const float* __restrict__ bias,
    float* __restrict__ h_glb,
    __hip_bfloat16* __restrict__ outs,
    float* __restrict__ out_c, float* __restrict__ out_h)
{
    const int bid = blockIdx.x;
    const int gr  = bid & 63;
    const int s   = bid >> 6;
    const int tid = threadIdx.x;
    const int cg  = tid >> 2;              // col-pair {2cg, 2cg+1} of 256-col slice
    const int kq  = tid & 3;               // k-range [kq*64, kq*64+64)
    const int lc0 = cg * 2;
    const int gate = lc0 >> 6;
    const int j0   = lc0 & 63;
    const int gcol0 = gate * 256 + s * 64 + j0;

    __shared__ __align__(16) float hC[2][4][68];    // [chain][kq sect(+4 pad)]
    __shared__ __align__(16) float xA[44];          // x chain A (single-buffer)
    __shared__ __align__(16) float xB2[2][44];      // x chain B (double-buffer)
    __shared__ __align__(16) float gA[256], gB[256];

    for (int i = tid; i < 2 * 4 * 68; i += 512) ((float*)hC)[i] = 0.0f;  // h(-1)=0
    if (tid < 44) xA[tid] = 0.0f;
    if (tid >= 64 && tid < 152) ((float*)xB2)[tid - 64] = 0.0f;

    // ---- persistent weights in VGPRs (loaded once, pinned vs remat) ----
    float2v W2[64];
    #pragma unroll
    for (int i = 0; i < 64; ++i) {
        const size_t r = (size_t)(kq * 64 + i) * G_DIM;
        W2[i].x = Wh[r + gcol0];
        W2[i].y = Wh[r + gcol0 + 1];
    }
    float2v X2[10];
    #pragma unroll
    for (int i = 0; i < 10; ++i) {
        int xk = kq * 10 + i;
        bool ok = (xk < IN_D);
        X2[i].x = ok ? Wx[(size_t)xk * G_DIM + gcol0]     : 0.0f;
        X2[i].y = ok ? Wx[(size_t)xk * G_DIM + gcol0 + 1] : 0.0f;
    }
    #pragma unroll
    for (int i = 0; i < 64; ++i) asm volatile("" : "+v"(W2[i]));
    #pragma unroll
    for (int i = 0; i < 10; ++i) asm volatile("" : "+v"(X2[i]));

    // writer roles: wave0 = chain A, wave1 = chain B; lane j = h-col of slice
    const int wj = tid & 63;
    float bc0 = 0, bc1 = 0, bc2 = 0, bc3 = 0;
    if (tid < 128) {
        bc0 = bias[0 * 256 + s * 64 + wj];
        bc1 = bias[1 * 256 + s * 64 + wj];
        bc2 = bias[2 * 256 + s * 64 + wj];
        bc3 = bias[3 * 256 + s * 64 + wj];
    }
    float c_reg = 0.0f;

    // poller role (tid in [128,320)): one foreign dword per chain
    const bool isp = (tid >= 128 && tid < 320);
    const int  pp  = tid - 128;                          // 0..191
    const int  pkk = pp + ((pp >= s * 64) ? 64 : 0);     // skip own 64-chunk
    unsigned pA = 0, pB = 0;                             // probe registers

    // stager role (tid in [384,454)): one (batch,k) each, 2-deep x reg pipeline
    const int  sq    = tid - 384;
    const bool is_st = (sq >= 0 && sq < 2 * IN_D);
    const int  sb    = (sq >= IN_D) ? 1 : 0;
    const int  sk    = sq - IN_D * sb;
    float xv_next = 0.0f;

    const int batch0 = gr * 2;
    float* hg  = h_glb + (size_t)gr * 1024;   // [chain][par][256]
    float* hgA = hg;
    float* hgB = hg + 512;

    // ---- prologue: x(0) direct, x(1) -> reg ----
    if (is_st) {
        const size_t rb = (size_t)(batch0 + sb) * T_LEN;
        float v0 = (sk < 32) ? z_t[(rb + 0) * 32 + sk] : a_t[(rb + 0) * 3 + (sk - 32)];
        if (sb == 0) xA[sk] = v0; else xB2[0][sk] = v0;
        xv_next = (sk < 32) ? z_t[(rb + 1) * 32 + sk] : a_t[(rb + 1) * 3 + (sk - 32)];
    }
    __syncthreads();

    for (int t = 0; t < T_LEN; ++t) {
        // ---- check P_A (h_A(t-1)); probes completed at last iter's barrier drain ----
        if (t > 0 && isp) {
            const unsigned want = (unsigned)((t - 1) & 3);
            asm volatile("s_waitcnt vmcnt(0)" : "+v"(pA) :: "memory");
            if ((pA & 3u) != want) {
                const float* ap = hgA + ((t - 1) & 1) * 256 + pkk;
                do {
                    asm volatile("global_load_dword %0, %1, off sc0 sc1\n\t"
                                 "s_waitcnt vmcnt(0)"
                                 : "=v"(pA) : "v"(ap) : "memory");
                } while ((pA & 3u) != want);
            }
            hC[0][pkk >> 6][pkk & 63] = __uint_as_float(pA);
        }
        __syncthreads();   // B1a: hC[0] + xA(t) ready

        // stagers: issue x(t+2) loads (arrive under FMA_A, drained by B2a)
        float xv_new = 0.0f;
        if (is_st && t + 2 < T_LEN) {
            const size_t rb = (size_t)(batch0 + sb) * T_LEN;
            xv_new = (sk < 32) ? z_t[(rb + t + 2) * 32 + sk]
                               : a_t[(rb + t + 2) * 3 + (sk - 32)];
        }

        // ---- FMA_A ----
        float2v acc = {0.0f, 0.0f};
        {
            const float4v* hp = (const float4v*)hC[0][kq];
            #pragma unroll
            for (int i4 = 0; i4 < 16; ++i4) {
                float4v hv = hp[i4];
                float2v lo = __builtin_shufflevector(hv, hv, 0, 1);
                float2v hi = __builtin_shufflevector(hv, hv, 2, 3);
                pk_fma_lo(acc, W2[4*i4+0], lo);
                pk_fma_hi(acc, W2[4*i4+1], lo);
                pk_fma_lo(acc, W2[4*i4+2], hi);
                pk_fma_hi(acc, W2[4*i4+3], hi);
            }
            // issue P_B probes (h_B(t-1), published a half-loop ago -> first-sample hit)
            if (isp && t > 0) {
                const float* ap = hgB + ((t - 1) & 1) * 256 + pkk;
                asm volatile("global_load_dword %0, %1, off sc0 sc1"
                             : "=v"(pB) : "v"(ap) : "memory");
            }
            #pragma unroll
            for (int i = 0; i < 5; ++i) {
                float2v xv = *(const float2v*)&xA[kq * 10 + 2 * i];
                pk_fma_lo(acc, X2[2*i],   xv);
                pk_fma_hi(acc, X2[2*i+1], xv);
            }
        }
        {
            float a0 = acc.x, a1 = acc.y;
            a0 += __shfl_xor(a0, 1, 64); a0 += __shfl_xor(a0, 2, 64);
            a1 += __shfl_xor(a1, 1, 64); a1 += __shfl_xor(a1, 2, 64);
            if (kq == 0) { gA[lc0] = a0; gA[lc0 + 1] = a1; }
        }
        __syncthreads();   // B2a: gA ready; P_B + x(t+2) loads drained

        // ---- wave0: nonlin + publish A(t) ----
        if (tid < 64) {
            float gi = gA[wj] + bc0, gf = gA[64 + wj] + bc1;
            float gg = gA[128 + wj] + bc2, go = gA[192 + wj] + bc3;
            float iv = fast_sigmoid(gi), fv = fast_sigmoid(gf), ov = fast_sigmoid(go);
            float gv = fast_tanh(gg);
            c_reg = fmaf(fv, c_reg, iv * gv);
            float hv = ov * fast_tanh(c_reg);
            unsigned u = (__float_as_uint(hv) & ~3u) | (unsigned)(t & 3);
            float* dst = hgA + (t & 1) * 256 + s * 64 + wj;
            asm volatile("global_store_dword %0, %1, off sc0 sc1"
                         :: "v"(dst), "v"(u) : "memory");
            hC[0][s][wj] = __uint_as_float(u);   // own slice: no IC round trip
            outs[((size_t)batch0 * T_LEN + t) * H_DIM + s * 64 + wj] = __float2bfloat16(hv);
            if (t == T_LEN - 1) {
                out_c[batch0 * H_DIM + s * 64 + wj] = c_reg;
                out_h[batch0 * H_DIM + s * 64 + wj] = hv;
            }
        }
        // ---- pollers: check P_B -> hC[1] ----
        if (isp && t > 0) {
            const unsigned want = (unsigned)((t - 1) & 3);
            asm volatile("s_waitcnt vmcnt(0)" : "+v"(pB) :: "memory");
            if ((pB & 3u) != want) {
                const float* ap = hgB + ((t - 1) & 1) * 256 + pkk;
                do {
                    asm volatile("global_load_dword %0, %1, off sc0 sc1\n\t"
                                 "s_waitcnt vmcnt(0)"
                                 : "=v"(pB) : "v"(ap) : "memory");
                } while ((pB & 3u) != want);
            }
            hC[1][pkk >> 6][pkk & 63] = __uint_as_float(pB);
        }
        // ---- stagers: write x(t+1) (xA read finished at B2a; xB double-buffered) ----
        if (is_st && t + 1 < T_LEN) {
            if (sb == 0) xA[sk] = xv_next;
            else         xB2[(t + 1) & 1][sk] = xv_next;
            xv_next = xv_new;
        }
        __syncthreads();   // B1b: hC[1] + xB2[t&1] ready

        // ---- FMA_B ----
        acc.x = 0.0f; acc.y = 0.0f;
        {
            const float4v* hp = (const float4v*)hC[1][kq];
            #pragma unroll
            for (int i4 = 0; i4 < 16; ++i4) {
                float4v hv = hp[i4];
                float2v lo = __builtin_shufflevector(hv, hv, 0, 1);
                float2v hi = __builtin_shufflevector(hv, hv, 2, 3);
                pk_fma_lo(acc, W2[4*i4+0], lo);
                pk_fma_hi(acc, W2[4*i4+1], lo);
                pk_fma_lo(acc, W2[4*i4+2], hi);
                pk_fma_hi(acc, W2[4*i4+3], hi);
            }
            // issue P_A probes (h_A(t), published ~600 cy ago -> likely hit)
            if (isp) {
                const float* ap = hgA + (t & 1) * 256 + pkk;
                asm volatile("global_load_dword %0, %1, off sc0 sc1"
                             : "=v"(pA) : "v"(ap) : "memory");
            }
            const float* xb = xB2[t & 1];
            #pragma unroll
            for (int i = 0; i < 5; ++i) {
                float2v xv = *(const float2v*)&xb[kq * 10 + 2 * i];
                pk_fma_lo(acc, X2[2*i],   xv);
                pk_fma_hi(acc, X2[2*i+1], xv);
            }
        }
        {
            float a0 = acc.x, a1 = acc.y;
            a0 += __shfl_xor(a0, 1, 64); a0 += __shfl_xor(a0, 2, 64);
            a1 += __shfl_xor(a1, 1, 64); a1 += __shfl_xor(a1, 2, 64);
            if (kq == 0) { gB[lc0] = a0; gB[lc0 + 1] = a1; }
        }
        __syncthreads();   // B2b: gB ready; P_A probes drained

        // ---- wave1: nonlin + publish B(t) ----
        if (tid >= 64 && tid < 128) {
            float gi = gB[wj] + bc0, gf = gB[64 + wj] + bc1;
            float gg = gB[128 + wj] + bc2, go = gB[192 + wj] + bc3;
            float iv = fast_sigmoid(gi), fv = fast_sigmoid(gf), ov = fast_sigmoid(go);
            float gv = fast_tanh(gg);
            c_reg = fmaf(fv, c_reg, iv * gv);
            float hv = ov * fast_tanh(c_reg);
            unsigned u = (__float_as_uint(hv) & ~3u) | (unsigned)(t & 3);
            float* dst = hgB + (t & 1) * 256 + s * 64 + wj;
            asm volatile("global_store_dword %0, %1, off sc0 sc1"
                         :: "v"(dst), "v"(u) : "memory");
            hC[1][s][wj] = __uint_as_float(u);
            outs[((size_t)(batch0 + 1) * T_LEN + t) * H_DIM + s * 64 + wj] =
                __float2bfloat16(hv);
            if (t == T_LEN - 1) {
                out_c[(batch0 + 1) * H_DIM + s * 64 + wj] = c_reg;
                out_h[(batch0 + 1) * H_DIM + s * 64 + wj] = hv;
            }
        }
        // loop: next B1a orders hC[1] own-write and xA/xB2 stager writes
    }
}

// mdn = outputs(bf16) @ Wd + bd, fused log_softmax(log_pi) and exp(log_sigma)+1e-6.
// (r6-proven 16-row version, ~107 us)
__global__ __launch_bounds__(256, 1) void mdn_kernel(
    const unsigned short* __restrict__ outputs, const float* __restrict__ Wd,
    const float* __restrict__ bd, float* __restrict__ out)
{
    __shared__ __align__(16) float hT[H_DIM * 16];   // hT[k*16 + r]
    __shared__ float lp[16][K_MIX];

    const int tid = threadIdx.x;
    const long row0 = (long)blockIdx.x * 16;

    for (int idx = tid; idx < H_DIM * 16; idx += 256) {
        int r = idx >> 8;
        int k = idx & (H_DIM - 1);
        unsigned int u = outputs[(row0 + r) * H_DIM + k];
        hT[k * 16 + r] = __uint_as_float(u << 16);
    }
    __syncthreads();

    const int  cA = tid;
    const int  cB = tid + 256;
    const bool vB = (cB < MDN_D);
    const float bA = bd[cA];
    const float bB = vB ? bd[cB] : 0.0f;
    float accA[16], accB[16];
    #pragma unroll
    for (int r = 0; r < 16; ++r) { accA[r] = bA; accB[r] = bB; }

    for (int k = 0; k < H_DIM; ++k) {
        float wA = Wd[(size_t)k * MDN_D + cA];
        float wB = vB ? Wd[(size_t)k * MDN_D + cB] : 0.0f;
        const float4* hp = (const float4*)(hT + k * 16);
        float4 h0 = hp[0], h1 = hp[1], h2 = hp[2], h3 = hp[3];
        float hr[16] = { h0.x,h0.y,h0.z,h0.w, h1.x,h1.y,h1.z,h1.w,
                         h2.x,h2.y,h2.z,h2.w, h3.x,h3.y,h3.z,h3.w };
        #pragma unroll
        for (int r = 0; r < 16; ++r) {
            accA[r] = fmaf(hr[r], wA, accA[r]);
            accB[r] = fmaf(hr[r], wB, accB[r]);
        }
    }

    float* out_mu = out + OFF_MU;
    float* out_sg = out + OFF_SIGMA;
    #pragma unroll
    for (int r = 0; r < 16; ++r) {
        long row = row0 + r;
        float v = accA[r];
        if (cA < K_MIX)            lp[r][cA] = v;
        else if (cA < K_MIX + 160) out_mu[row * 160 + (cA - K_MIX)] = v;
        else                       out_sg[row * 160 + (cA - 165)]   = __expf(v) + 1e-6f;
        if (vB)                    out_sg[row * 160 + (cB - 165)]   = __expf(accB[r]) + 1e-6f;
    }
    __syncthreads();

    if (tid < 16) {
        int r = tid;
        long row = row0 + r;
        float v0 = lp[r][0], v1 = lp[r][1], v2 = lp[r][2], v3 = lp[r][3], v4 = lp[r][4];
        float m = fmaxf(fmaxf(fmaxf(v0, v1), fmaxf(v2, v3)), v4);
        float sum = __expf(v0-m) + __expf(v1-m) + __expf(v2-m) + __expf(v3-m) + __expf(v4-m);
        float ls = m + __logf(sum);
        out[row*5 + 0] = v0 - ls;
        out[row*5 + 1] = v1 - ls;
        out[row*5 + 2] = v2 - ls;
        out[row*5 + 3] = v3 - ls;
        out[row*5 + 4] = v4 - ls;
    }
}

extern "C" void kernel_launch(void* const* d_in, const int* in_sizes, int n_in,
                              void* d_out, int out_size, void* d_ws, size_t ws_size,
                              hipStream_t stream)
{
    const float* z_t = (const float*)d_in[0];
    const float* a_t = (const float*)d_in[1];
    const float* Wx  = (const float*)d_in[2];
    const float* Wh  = (const float*)d_in[3];
    const float* b   = (const float*)d_in[4];
    const float* Wd  = (const float*)d_in[5];
    const float* bd  = (const float*)d_in[6];
    float* out = (float*)d_out;

    char* ws = (char*)d_ws;
    __hip_bfloat16* outs = (__hip_bfloat16*)(ws + WS_OUT);
    float* h_glb         = (float*)(ws + WS_HG);

    lstm11_kernel<<<NGRP * NSLICE, 512, 0, stream>>>(z_t, a_t, Wx, Wh, b,
                                                     h_glb, outs,
                                                     out + OFF_C, out + OFF_H);
    mdn_kernel<<<(B_SZ * T_LEN) / 16, 256, 0, stream>>>((const unsigned short*)outs,
                                                        Wd, bd, out);
}